// Round 8
// baseline (240.918 us; speedup 1.0000x reference)
//
#include <hip/hip_runtime.h>
#include <hip/hip_bf16.h>
#include <hip/hip_fp16.h>
#include <stdint.h>

typedef __attribute__((ext_vector_type(8))) _Float16 f16x8;
typedef __attribute__((ext_vector_type(4))) float f32x4;
typedef __attribute__((ext_vector_type(4))) int i32x4;

// ---------------- W fp32 -> fp16 (into workspace), 512x2048 -------------
__global__ __launch_bounds__(256) void k_cvt_w(const float* __restrict__ W,
                                               _Float16* __restrict__ Wh) {
  int i = (blockIdx.x * 256 + threadIdx.x) * 8;  // 1048576 elems total
  float4 a = *(const float4*)(W + i);
  float4 b = *(const float4*)(W + i + 4);
  union { _Float16 h[8]; i32x4 v; } u;
  u.h[0] = (_Float16)a.x; u.h[1] = (_Float16)a.y;
  u.h[2] = (_Float16)a.z; u.h[3] = (_Float16)a.w;
  u.h[4] = (_Float16)b.x; u.h[5] = (_Float16)b.y;
  u.h[6] = (_Float16)b.z; u.h[7] = (_Float16)b.w;
  *(i32x4*)(Wh + i) = u.v;
}

__device__ inline float softplus_f(float x) {
  float e = __expf(-fabsf(x));
  return fmaxf(x, 0.f) + __logf(1.f + e);
}

// ---- fused GEMM(fp16 MFMA, zero-LDS, zero-barrier) + softplus partial ----
// Block 64 rows x 256 hid cols (N-split 2), 8 waves 2Mx4N, wave-tile 32x64.
// Both MFMA fragments = 8 consecutive k at fixed row -> direct global->VGPR
// loads are 64-128B coalesced per quarter-wave. W fp16 (2MB) is L2-resident;
// A-tile reuse via L1. Register double-buffer, prefetch distance 1; latency
// hidden by 4 independent waves/SIMD (no lockstep barriers).
__global__ __launch_bounds__(512, 4) void k_main(
    const float* __restrict__ X,      // [16384][2048]
    const _Float16* __restrict__ Wh,  // [512][2048]
    const float* __restrict__ U,      // [512][2]
    const float* __restrict__ hb,     // [512]
    float* __restrict__ Dp) {         // [2][16384] partial logit-diffs
  __shared__ float sD[64];

  const int t = threadIdx.x;
  const int lane = t & 63;
  const int wid = t >> 6;   // 0..7
  const int wm = wid >> 2;  // 0..1 (M half)
  const int wn = wid & 3;   // 0..3 (N quarter)
  const int bx = blockIdx.x;
  const int bm0 = (bx >> 1) * 64;
  const int nhalf = bx & 1;
  const int bn0 = nhalf * 256;
  const int lrow = lane & 15, lq = lane >> 4;

  if (t < 64) sD[t] = 0.f;
  __syncthreads();

  f32x4 acc[2][4];
#pragma unroll
  for (int m = 0; m < 2; ++m)
#pragma unroll
    for (int n = 0; n < 4; ++n) acc[m][n] = (f32x4){0.f, 0.f, 0.f, 0.f};

  // Fragment bases: lane reads its row (lrow within 16-row frag) at
  // k = lq*8 .. lq*8+7 within the 32-k step (validated layout R1-R7).
  const float* aptr = X + (size_t)(bm0 + wm * 32 + lrow) * 2048 + lq * 8;
  const _Float16* bptr =
      Wh + (size_t)(bn0 + wn * 64 + lrow) * 2048 + lq * 8;

  f32x4 arA[2][2], arB[2][2];  // A raw fp32, two reg sets (dbuf)
  f16x8 bfA[4], bfB[4];        // B frags, two reg sets

#define LOAD_A_SET(AR, KK) do {                                            \
    _Pragma("unroll") for (int mf = 0; mf < 2; ++mf) {                     \
      const float* p = aptr + mf * 32768 + (size_t)(KK) * 32;              \
      AR[mf][0] = *(const f32x4*)p;                                        \
      AR[mf][1] = *(const f32x4*)(p + 4);                                  \
    }                                                                      \
  } while (0)

#define LOAD_B_SET(BF, KK) do {                                            \
    _Pragma("unroll") for (int nf = 0; nf < 4; ++nf)                       \
      BF[nf] = *(const f16x8*)(bptr + nf * 32768 + (size_t)(KK) * 32);     \
  } while (0)

#define COMP_SET(AR, BF) do {                                              \
    f16x8 fa[2];                                                           \
    _Pragma("unroll") for (int mf = 0; mf < 2; ++mf)                       \
      _Pragma("unroll") for (int j = 0; j < 4; ++j) {                      \
        fa[mf][j] = (_Float16)AR[mf][0][j];                                \
        fa[mf][j + 4] = (_Float16)AR[mf][1][j];                            \
      }                                                                    \
    _Pragma("unroll") for (int mf = 0; mf < 2; ++mf)                       \
      _Pragma("unroll") for (int nf = 0; nf < 4; ++nf)                     \
        acc[mf][nf] = __builtin_amdgcn_mfma_f32_16x16x32_f16(              \
            fa[mf], BF[nf], acc[mf][nf], 0, 0, 0);                         \
  } while (0)

  // prologue: set A <- k-step 0
  LOAD_A_SET(arA, 0);
  LOAD_B_SET(bfA, 0);

  for (int kk = 0; kk < 64; kk += 2) {
    // prefetch k-step kk+1 into set B, compute kk from set A
    LOAD_A_SET(arB, kk + 1);
    LOAD_B_SET(bfB, kk + 1);
    COMP_SET(arA, bfA);
    // prefetch k-step kk+2 into set A (clamped dup at tail), compute kk+1
    const int kn = (kk + 2 > 63) ? 63 : kk + 2;
    LOAD_A_SET(arA, kn);
    LOAD_B_SET(bfA, kn);
    COMP_SET(arB, bfB);
  }
#undef LOAD_A_SET
#undef LOAD_B_SET
#undef COMP_SET

  // ---- epilogue: softplus-difference partial for this N-half ----
  // acc[mf][nf][r]: row = bm0 + wm*32 + mf*16 + lq*4 + r
  //                 col = bn0 + wn*64 + nf*16 + lrow
  float dpart[8];
#pragma unroll
  for (int i = 0; i < 8; ++i) dpart[i] = 0.f;
#pragma unroll
  for (int nf = 0; nf < 4; ++nf) {
    int h = bn0 + wn * 64 + nf * 16 + lrow;
    float hbv = hb[h];
    float u0 = U[2 * h], u1 = U[2 * h + 1];
#pragma unroll
    for (int mf = 0; mf < 2; ++mf)
#pragma unroll
      for (int r = 0; r < 4; ++r) {
        float pf = acc[mf][nf][r] + hbv;
        dpart[mf * 4 + r] += softplus_f(pf + u0) - softplus_f(pf + u1);
      }
  }
#pragma unroll
  for (int i = 0; i < 8; ++i) {
    float v = dpart[i];
    v += __shfl_xor(v, 1);
    v += __shfl_xor(v, 2);
    v += __shfl_xor(v, 4);
    v += __shfl_xor(v, 8);
    dpart[i] = v;
  }
  if (lrow == 0) {
#pragma unroll
    for (int mf = 0; mf < 2; ++mf)
#pragma unroll
      for (int r = 0; r < 4; ++r)
        atomicAdd(&sD[wm * 32 + mf * 16 + lq * 4 + r], dpart[mf * 4 + r]);
  }
  __syncthreads();
  if (t < 64) Dp[nhalf * 16384 + bm0 + t] = sD[t];
}

// ---- combine the two N-half partials + sigmoid ----
__global__ __launch_bounds__(256) void k_final(const float* __restrict__ Dp,
                                               const float* __restrict__ yb,
                                               float* __restrict__ out) {
  int i = blockIdx.x * 256 + threadIdx.x;  // 0..16383
  float D = Dp[i] + Dp[16384 + i] + yb[0] - yb[1];  // logit0 - logit1
  float e = __expf(-D);
  float o0 = 1.f / (1.f + e);
  float o1 = e * o0;
  *(float2*)(out + (size_t)i * 2) = make_float2(o0, o1);
}

extern "C" void kernel_launch(void* const* d_in, const int* in_sizes, int n_in,
                              void* d_out, int out_size, void* d_ws,
                              size_t ws_size, hipStream_t stream) {
  const float* X = (const float*)d_in[0];
  const float* W = (const float*)d_in[1];
  const float* U = (const float*)d_in[2];
  const float* hb = (const float*)d_in[3];
  const float* yb = (const float*)d_in[4];
  float* out = (float*)d_out;
  _Float16* Wh = (_Float16*)d_ws;                       // 2 MB
  float* Dp = (float*)((char*)d_ws + 2 * 1024 * 1024);  // 128 KB partials

  hipLaunchKernelGGL(k_cvt_w, dim3(512), dim3(256), 0, stream, W, Wh);
  hipLaunchKernelGGL(k_main, dim3(512), dim3(512), 0, stream, X, Wh, U, hb, Dp);
  hipLaunchKernelGGL(k_final, dim3(64), dim3(256), 0, stream, Dp, yb, out);
}

// Round 9
// 148.072 us; speedup vs baseline: 1.6270x; 1.6270x over previous
//
#include <hip/hip_runtime.h>
#include <hip/hip_bf16.h>
#include <hip/hip_fp16.h>
#include <stdint.h>

typedef __attribute__((ext_vector_type(8))) _Float16 f16x8;
typedef __attribute__((ext_vector_type(4))) float f32x4;
typedef __attribute__((ext_vector_type(4))) int i32x4;

#define GLD_LDS16(g, l) __builtin_amdgcn_global_load_lds( \
    (const __attribute__((address_space(1))) uint32_t*)(g), \
    (__attribute__((address_space(3))) uint32_t*)(l), 16, 0, 0)

// ---------------- W fp32 -> fp16 (into workspace), 512x2048 -------------
__global__ __launch_bounds__(256) void k_cvt_w(const float* __restrict__ W,
                                               _Float16* __restrict__ Wh) {
  int i = (blockIdx.x * 256 + threadIdx.x) * 8;  // 1048576 elems total
  float4 a = *(const float4*)(W + i);
  float4 b = *(const float4*)(W + i + 4);
  union { _Float16 h[8]; i32x4 v; } u;
  u.h[0] = (_Float16)a.x; u.h[1] = (_Float16)a.y;
  u.h[2] = (_Float16)a.z; u.h[3] = (_Float16)a.w;
  u.h[4] = (_Float16)b.x; u.h[5] = (_Float16)b.y;
  u.h[6] = (_Float16)b.z; u.h[7] = (_Float16)b.w;
  *(i32x4*)(Wh + i) = u.v;
}

__device__ inline float softplus_f(float x) {
  float e = __expf(-fabsf(x));
  return fmaxf(x, 0.f) + __logf(1.f + e);
}

// ---- fused GEMM + softplus-diff + sigmoid: barrier-free wave pipelines ----
// Grid 256, block = 64 rows x 512 cols, 8 waves; wave wid owns cols
// [wid*64, wid*64+64) for ALL 64 rows (acc 4x4, 16 MFMA/step, BK=32).
// A: direct global->reg (all 8 waves read the same 64 rows -> L1-served),
//    cvt fp32->fp16 in-register. Never touches LDS.
// B: wave-PRIVATE gld_lds staging (4KB/wave/panel, dbuf) -> stage own,
//    read own -> NO __syncthreads in the K-loop. Ordering: per-wave
//    program order + vmcnt(12) (12 = the t+1 ops just issued).
__global__ __launch_bounds__(512, 2) void k_main(
    const float* __restrict__ X,      // [16384][2048]
    const _Float16* __restrict__ Wh,  // [512][2048]
    const float* __restrict__ U,      // [512][2]
    const float* __restrict__ hb,     // [512]
    const float* __restrict__ yb,     // [2]
    float* __restrict__ out) {        // [16384][2]
  __shared__ __align__(16) _Float16 Bs[2][8][2048];  // 2 x 8 x 4KB = 64KB
  __shared__ float sD[64];

  const int t = threadIdx.x;
  const int lane = t & 63;
  const int wid = t >> 6;  // 0..7: owns cols [wid*64, wid*64+64)
  const int bm0 = blockIdx.x * 64;
  const int lrow = lane & 15, lq = lane >> 4;

  if (t < 64) sD[t] = 0.f;
  __syncthreads();

  f32x4 acc[4][4];
#pragma unroll
  for (int m = 0; m < 4; ++m)
#pragma unroll
    for (int n = 0; n < 4; ++n) acc[m][n] = (f32x4){0.f, 0.f, 0.f, 0.f};

  // B staging source (pre-swizzled global, m173): gld_lds writes lane l at
  // base + l*16 = row (l>>2)*64B + phys slot (l&3)*16B. Phys slot s of row
  // rl must hold logical chunk s ^ (rl&3)  (bijective slot swizzle).
  const int bq = lane >> 2, bs3 = lane & 3;
  const int bc = bs3 ^ (bq & 3);
  const _Float16* bsrc = Wh + (size_t)(wid * 64 + bq) * 2048 + bc * 8;
  char* const bdst0 = (char*)&Bs[0][wid][0];
  char* const bdst1 = (char*)&Bs[1][wid][0];

  // A direct-load bases: lane -> row (mf*16 + lrow), k = lq*8 + [0..7].
  const float* aptr = X + (size_t)(bm0 + lrow) * 2048 + lq * 8;

  f32x4 arA[4][2], arB[4][2];  // A fp32 raw, two named sets (rule #20)

#define ISSUE_B(DST, KB) do {                                              \
    _Pragma("unroll") for (int i = 0; i < 4; ++i)                          \
      GLD_LDS16(bsrc + (size_t)i * 16 * 2048 + (size_t)(KB) * 32,          \
                (DST) + i * 1024);                                         \
  } while (0)

#define ISSUE_A(AR, KA) do {                                               \
    _Pragma("unroll") for (int mf = 0; mf < 4; ++mf) {                     \
      const float* p = aptr + (size_t)mf * 16 * 2048 + (size_t)(KA) * 32;  \
      AR[mf][0] = *(const f32x4*)p;                                        \
      AR[mf][1] = *(const f32x4*)(p + 4);                                  \
    }                                                                      \
  } while (0)

  // One K-step: issue B(KN)+A(KN) (12 VMEM ops), cvt A(KT), vmcnt(12)
  // (=> B(KT)/A(KT), strictly older, complete), ds_read B(KT), 16 MFMA.
#define STEP(ARC, ARN, BCUR, BNXT, KN) do {                                \
    ISSUE_B(BNXT, KN);                                                     \
    __builtin_amdgcn_sched_barrier(0);                                     \
    ISSUE_A(ARN, KN);                                                      \
    __builtin_amdgcn_sched_barrier(0);                                     \
    f16x8 fa[4];                                                           \
    _Pragma("unroll") for (int mf = 0; mf < 4; ++mf)                       \
      _Pragma("unroll") for (int j = 0; j < 4; ++j) {                      \
        fa[mf][j] = (_Float16)ARC[mf][0][j];                               \
        fa[mf][j + 4] = (_Float16)ARC[mf][1][j];                           \
      }                                                                    \
    asm volatile("s_waitcnt vmcnt(12)" ::: "memory");                      \
    __builtin_amdgcn_sched_barrier(0);                                     \
    f16x8 fb[4];                                                           \
    _Pragma("unroll") for (int nf = 0; nf < 4; ++nf) {                     \
      int rl = nf * 16 + lrow;                                             \
      int off = rl * 64 + ((lq ^ (rl & 3)) << 4);                          \
      fb[nf] = *(const f16x8*)((const char*)(BCUR) + off);                 \
    }                                                                      \
    __builtin_amdgcn_s_setprio(1);                                         \
    _Pragma("unroll") for (int mf = 0; mf < 4; ++mf)                       \
      _Pragma("unroll") for (int nf = 0; nf < 4; ++nf)                     \
        acc[mf][nf] = __builtin_amdgcn_mfma_f32_16x16x32_f16(              \
            fa[mf], fb[nf], acc[mf][nf], 0, 0, 0);                         \
    __builtin_amdgcn_s_setprio(0);                                         \
  } while (0)

  // ---- prologue: B(0) -> buf0, A(0) -> setA ----
  ISSUE_B(bdst0, 0);
  ISSUE_A(arA, 0);

  for (int kt = 0; kt < 64; kt += 2) {
    STEP(arA, arB, bdst0, bdst1, kt + 1);               // consume kt
    const int kn = (kt + 2 > 63) ? 63 : kt + 2;         // tail-clamped
    STEP(arB, arA, bdst1, bdst0, kn);                   // consume kt+1
  }
#undef STEP
#undef ISSUE_A
#undef ISSUE_B

  // ---- epilogue: softplus-difference, per-row reduce, sigmoid ----
  // acc[mf][nf][r]: row = bm0 + mf*16 + lq*4 + r
  //                 col = wid*64 + nf*16 + lrow
  float dpart[16];
#pragma unroll
  for (int i = 0; i < 16; ++i) dpart[i] = 0.f;
#pragma unroll
  for (int nf = 0; nf < 4; ++nf) {
    int h = wid * 64 + nf * 16 + lrow;
    float hbv = hb[h];
    float u0 = U[2 * h], u1 = U[2 * h + 1];
#pragma unroll
    for (int mf = 0; mf < 4; ++mf)
#pragma unroll
      for (int r = 0; r < 4; ++r) {
        float pf = acc[mf][nf][r] + hbv;
        dpart[mf * 4 + r] += softplus_f(pf + u0) - softplus_f(pf + u1);
      }
  }
#pragma unroll
  for (int i = 0; i < 16; ++i) {
    float v = dpart[i];
    v += __shfl_xor(v, 1);
    v += __shfl_xor(v, 2);
    v += __shfl_xor(v, 4);
    v += __shfl_xor(v, 8);
    dpart[i] = v;
  }
  if (lrow == 0) {
#pragma unroll
    for (int mf = 0; mf < 4; ++mf)
#pragma unroll
      for (int r = 0; r < 4; ++r)
        atomicAdd(&sD[mf * 16 + lq * 4 + r], dpart[mf * 4 + r]);
  }
  __syncthreads();
  if (t < 64) {
    float Dl = sD[t] + yb[0] - yb[1];  // logit0 - logit1
    float e = __expf(-Dl);
    float o0 = 1.f / (1.f + e);
    float o1 = e * o0;
    *(float2*)(out + (size_t)(bm0 + t) * 2) = make_float2(o0, o1);
  }
}

extern "C" void kernel_launch(void* const* d_in, const int* in_sizes, int n_in,
                              void* d_out, int out_size, void* d_ws,
                              size_t ws_size, hipStream_t stream) {
  const float* X = (const float*)d_in[0];
  const float* W = (const float*)d_in[1];
  const float* U = (const float*)d_in[2];
  const float* hb = (const float*)d_in[3];
  const float* yb = (const float*)d_in[4];
  float* out = (float*)d_out;
  _Float16* Wh = (_Float16*)d_ws;  // 2 MB scratch

  hipLaunchKernelGGL(k_cvt_w, dim3(512), dim3(256), 0, stream, W, Wh);
  hipLaunchKernelGGL(k_main, dim3(256), dim3(512), 0, stream, X, Wh, U, hb, yb,
                     out);
}

// Round 10
// 75.729 us; speedup vs baseline: 3.1813x; 1.9553x over previous
//
#include <hip/hip_runtime.h>
#include <hip/hip_bf16.h>
#include <hip/hip_fp16.h>
#include <stdint.h>

typedef __attribute__((ext_vector_type(8))) _Float16 f16x8;
typedef __attribute__((ext_vector_type(4))) float f32x4;
typedef __attribute__((ext_vector_type(4))) int i32x4;

#define GLD_LDS16(g, l) __builtin_amdgcn_global_load_lds( \
    (const __attribute__((address_space(1))) uint32_t*)(g), \
    (__attribute__((address_space(3))) uint32_t*)(l), 16, 0, 0)

// ---------------- W fp32 -> fp16 (into workspace), 512x2048 -------------
__global__ __launch_bounds__(256) void k_cvt_w(const float* __restrict__ W,
                                               _Float16* __restrict__ Wh) {
  int i = (blockIdx.x * 256 + threadIdx.x) * 8;  // 1048576 elems total
  float4 a = *(const float4*)(W + i);
  float4 b = *(const float4*)(W + i + 4);
  union { _Float16 h[8]; i32x4 v; } u;
  u.h[0] = (_Float16)a.x; u.h[1] = (_Float16)a.y;
  u.h[2] = (_Float16)a.z; u.h[3] = (_Float16)a.w;
  u.h[4] = (_Float16)b.x; u.h[5] = (_Float16)b.y;
  u.h[6] = (_Float16)b.z; u.h[7] = (_Float16)b.w;
  *(i32x4*)(Wh + i) = u.v;
}

__device__ inline float softplus_f(float x) {
  float e = __expf(-fabsf(x));
  return fmaxf(x, 0.f) + __logf(1.f + e);
}

// ---- fused GEMM(fp16 MFMA) + softplus-diff partial, FAT TILE ----
// Block 128 rows x 256 cols (N-split 2), BK=64, 32 K-steps, 512 thr.
// 8 waves 2Mx4N, wave-tile 64x64: 32 MFMA + 16 ds_read_b128 per step
// (4x the work-per-sync-point of R1-R9 -- the m201/m233 lesson).
// A: global->reg, cvt fp32->fp16 once, swizzled ds_write (2 x 16KB buf).
// B: gld_lds pre-swizzled source (2 x 32KB buf). Counted vmcnt schedule:
// per step issue [B(t+1)x4, A(t+2)x4]; vmcnt(8) before cvt (drains A(t+1));
// vmcnt(4)+lgkmcnt(0)+s_barrier at end (drains B(t+1); A(t+2) in flight).
__global__ __launch_bounds__(512, 2) void k_main(
    const float* __restrict__ X,      // [16384][2048]
    const _Float16* __restrict__ Wh,  // [512][2048]
    const float* __restrict__ U,      // [512][2]
    const float* __restrict__ hb,     // [512]
    float* __restrict__ Dp) {         // [2][16384] partial logit-diffs
  __shared__ __align__(16) _Float16 As[2][128 * 64];  // 2 x 16 KB
  __shared__ __align__(16) _Float16 Bs[2][256 * 64];  // 2 x 32 KB
  __shared__ float sD[128];

  const int t = threadIdx.x;
  const int lane = t & 63;
  const int wid = t >> 6;   // 0..7
  const int wm = wid >> 2;  // 0..1 (M half)
  const int wn = wid & 3;   // 0..3 (N quarter)
  const int bx = blockIdx.x;
  const int bm0 = (bx >> 1) * 128;
  const int nhalf = bx & 1;
  const int bn0 = nhalf * 256;
  const int lrow = lane & 15, lq = lane >> 4;

  if (t < 128) sD[t] = 0.f;
  __syncthreads();

  f32x4 acc[4][4];
#pragma unroll
  for (int m = 0; m < 4; ++m)
#pragma unroll
    for (int n = 0; n < 4; ++n) acc[m][n] = (f32x4){0.f, 0.f, 0.f, 0.f};

  // A staging: thread -> row t>>2 (0..127), k-chunk16 t&3. Writes 2 f16x8
  // at slots {2c, 2c+1} ^ (row&7)  (proven swizzle family, R4-R7).
  const int arow = t >> 2, ach = t & 3;
  const float* xsrc = X + (size_t)(bm0 + arow) * 2048 + ach * 16;
  const int c0 = ach * 2;
  const int aw0 = arow * 128 + (((c0) ^ (arow & 7)) << 4);
  const int aw1 = arow * 128 + (((c0 + 1) ^ (arow & 7)) << 4);

  // B staging: wave wid covers rows [wid*32, wid*32+32), 4 gld_lds of 1KB.
  // Pre-swizzled source (m173): phys slot s8 of row l8 holds chunk s8^l8.
  const int l8 = lane >> 3, s8 = lane & 7;
  const _Float16* bsrc =
      Wh + (size_t)(bn0 + wid * 32 + l8) * 2048 + (s8 ^ l8) * 8;
  char* const bd0 = (char*)&Bs[0][0] + wid * 4096;
  char* const bd1 = (char*)&Bs[1][0] + wid * 4096;

  f32x4 arA[4], arB[4];  // A fp32 raw, two named sets (static idx only)

#define CVT_WRITE_A(ARC, Q) do {                                           \
    f16x8 hv0, hv1;                                                        \
    _Pragma("unroll") for (int j = 0; j < 4; ++j) {                        \
      hv0[j] = (_Float16)ARC[0][j]; hv0[j + 4] = (_Float16)ARC[1][j];      \
      hv1[j] = (_Float16)ARC[2][j]; hv1[j + 4] = (_Float16)ARC[3][j];      \
    }                                                                      \
    *(f16x8*)((char*)&As[Q][0] + aw0) = hv0;                               \
    *(f16x8*)((char*)&As[Q][0] + aw1) = hv1;                               \
  } while (0)

  // One K-step (KT), P = KT&1 read bufs, Q = other: see header comment.
#define STEP(KT, P, Q, ARL, ARC, BDQ) do {                                 \
    const int kb_ = ((KT) + 1 > 31) ? 31 : (KT) + 1;                       \
    const int ka_ = ((KT) + 2 > 31) ? 31 : (KT) + 2;                       \
    _Pragma("unroll") for (int i = 0; i < 4; ++i)                          \
      GLD_LDS16(bsrc + (size_t)i * 16384 + (size_t)kb_ * 64,               \
                (BDQ) + i * 1024);                                         \
    _Pragma("unroll") for (int c = 0; c < 4; ++c)                          \
      ARL[c] = *(const f32x4*)(xsrc + (size_t)ka_ * 64 + c * 4);           \
    __builtin_amdgcn_sched_barrier(0);                                     \
    asm volatile("s_waitcnt vmcnt(8)" ::: "memory");                       \
    __builtin_amdgcn_sched_barrier(0);                                     \
    CVT_WRITE_A(ARC, Q);                                                   \
    f16x8 fa[4][2], fb[4][2];                                              \
    _Pragma("unroll") for (int mf = 0; mf < 4; ++mf) {                     \
      int row = wm * 64 + mf * 16 + lrow;                                  \
      _Pragma("unroll") for (int ks = 0; ks < 2; ++ks) {                   \
        int off = row * 128 + (((ks * 4 + lq) ^ (row & 7)) << 4);          \
        fa[mf][ks] = *(const f16x8*)((const char*)&As[P][0] + off);        \
      }                                                                    \
    }                                                                      \
    _Pragma("unroll") for (int nf = 0; nf < 4; ++nf) {                     \
      int row = wn * 64 + nf * 16 + lrow;                                  \
      _Pragma("unroll") for (int ks = 0; ks < 2; ++ks) {                   \
        int off = row * 128 + (((ks * 4 + lq) ^ (row & 7)) << 4);          \
        fb[nf][ks] = *(const f16x8*)((const char*)&Bs[P][0] + off);        \
      }                                                                    \
    }                                                                      \
    __builtin_amdgcn_sched_barrier(0);                                     \
    __builtin_amdgcn_s_setprio(1);                                         \
    _Pragma("unroll") for (int ks = 0; ks < 2; ++ks)                       \
      _Pragma("unroll") for (int mf = 0; mf < 4; ++mf)                     \
        _Pragma("unroll") for (int nf = 0; nf < 4; ++nf)                   \
          acc[mf][nf] = __builtin_amdgcn_mfma_f32_16x16x32_f16(            \
              fa[mf][ks], fb[nf][ks], acc[mf][nf], 0, 0, 0);               \
    __builtin_amdgcn_s_setprio(0);                                         \
    asm volatile("s_waitcnt vmcnt(4) lgkmcnt(0)" ::: "memory");            \
    __builtin_amdgcn_sched_barrier(0);                                     \
    __builtin_amdgcn_s_barrier();                                          \
  } while (0)

  // ---- prologue: A(0)->regsA, B(0)->buf0, A(1)->regsB; cvt A(0)->As[0] --
#pragma unroll
  for (int c = 0; c < 4; ++c) arA[c] = *(const f32x4*)(xsrc + c * 4);
#pragma unroll
  for (int i = 0; i < 4; ++i)
    GLD_LDS16(bsrc + (size_t)i * 16384, bd0 + i * 1024);
#pragma unroll
  for (int c = 0; c < 4; ++c) arB[c] = *(const f32x4*)(xsrc + 64 + c * 4);
  __builtin_amdgcn_sched_barrier(0);
  asm volatile("s_waitcnt vmcnt(8)" ::: "memory");  // A(0) landed
  __builtin_amdgcn_sched_barrier(0);
  CVT_WRITE_A(arA, 0);
  asm volatile("s_waitcnt lgkmcnt(0)" ::: "memory");
  __builtin_amdgcn_s_barrier();
  // entry state: outstanding [B(0)x4, A(1)x4]; As[0] staged.

  for (int kt = 0; kt < 32; kt += 2) {
    STEP(kt, 0, 1, arA, arB, bd1);      // consume tile kt
    STEP(kt + 1, 1, 0, arB, arA, bd0);  // consume tile kt+1
  }
#undef STEP
#undef CVT_WRITE_A

  // ---- epilogue: softplus-difference partial for this N-half ----
  // acc[mf][nf][r]: row = bm0 + wm*64 + mf*16 + lq*4 + r
  //                 col = bn0 + wn*64 + nf*16 + lrow
  float dpart[16];
#pragma unroll
  for (int i = 0; i < 16; ++i) dpart[i] = 0.f;
#pragma unroll
  for (int nf = 0; nf < 4; ++nf) {
    int h = bn0 + wn * 64 + nf * 16 + lrow;
    float hbv = hb[h];
    float u0 = U[2 * h], u1 = U[2 * h + 1];
#pragma unroll
    for (int mf = 0; mf < 4; ++mf)
#pragma unroll
      for (int r = 0; r < 4; ++r) {
        float pf = acc[mf][nf][r] + hbv;
        dpart[mf * 4 + r] += softplus_f(pf + u0) - softplus_f(pf + u1);
      }
  }
#pragma unroll
  for (int i = 0; i < 16; ++i) {
    float v = dpart[i];
    v += __shfl_xor(v, 1);
    v += __shfl_xor(v, 2);
    v += __shfl_xor(v, 4);
    v += __shfl_xor(v, 8);
    dpart[i] = v;
  }
  if (lrow == 0) {
#pragma unroll
    for (int mf = 0; mf < 4; ++mf)
#pragma unroll
      for (int r = 0; r < 4; ++r)
        atomicAdd(&sD[wm * 64 + mf * 16 + lq * 4 + r], dpart[mf * 4 + r]);
  }
  __syncthreads();
  if (t < 128) Dp[nhalf * 16384 + bm0 + t] = sD[t];
}

// ---- combine the two N-half partials + sigmoid ----
__global__ __launch_bounds__(256) void k_final(const float* __restrict__ Dp,
                                               const float* __restrict__ yb,
                                               float* __restrict__ out) {
  int i = blockIdx.x * 256 + threadIdx.x;  // 0..16383
  float D = Dp[i] + Dp[16384 + i] + yb[0] - yb[1];  // logit0 - logit1
  float e = __expf(-D);
  float o0 = 1.f / (1.f + e);
  float o1 = e * o0;
  *(float2*)(out + (size_t)i * 2) = make_float2(o0, o1);
}

extern "C" void kernel_launch(void* const* d_in, const int* in_sizes, int n_in,
                              void* d_out, int out_size, void* d_ws,
                              size_t ws_size, hipStream_t stream) {
  const float* X = (const float*)d_in[0];
  const float* W = (const float*)d_in[1];
  const float* U = (const float*)d_in[2];
  const float* hb = (const float*)d_in[3];
  const float* yb = (const float*)d_in[4];
  float* out = (float*)d_out;
  _Float16* Wh = (_Float16*)d_ws;                       // 2 MB
  float* Dp = (float*)((char*)d_ws + 2 * 1024 * 1024);  // 128 KB partials

  hipLaunchKernelGGL(k_cvt_w, dim3(512), dim3(256), 0, stream, W, Wh);
  hipLaunchKernelGGL(k_main, dim3(256), dim3(512), 0, stream, X, Wh, U, hb, Dp);
  hipLaunchKernelGGL(k_final, dim3(64), dim3(256), 0, stream, Dp, yb, out);
}